// Round 5
// baseline (725.944 us; speedup 1.0000x reference)
//
#include <hip/hip_runtime.h>
#include <hip/hip_bf16.h>
#include <stdint.h>

// ---------------------------------------------------------------------------
// f16 pair helpers — clang's amdgcn builtins use __fp16 vectors
// ---------------------------------------------------------------------------
typedef __fp16 half2v __attribute__((ext_vector_type(2)));

__device__ __forceinline__ half2v u2h(uint32_t u) {
    union { uint32_t u; half2v h; } c; c.u = u; return c.h;
}
__device__ __forceinline__ uint32_t pk(float lo, float hi) {
    union { uint32_t u; half2v h; } c;
    c.h = __builtin_amdgcn_cvt_pkrtz(lo, hi);
    return c.u;
}
#if __has_builtin(__builtin_amdgcn_fdot2)
__device__ __forceinline__ float dot2(uint32_t a, uint32_t b, float c) {
    return __builtin_amdgcn_fdot2(u2h(a), u2h(b), c, false);
}
#else
__device__ __forceinline__ float dot2(uint32_t a, uint32_t b, float c) {
    half2v ha = u2h(a), hb = u2h(b);
    c = fmaf((float)ha.x, (float)hb.x, c);
    c = fmaf((float)ha.y, (float)hb.y, c);
    return c;
}
#endif

// ---------------------------------------------------------------------------
// DPP helpers: reductions within each 16-lane row (VALU pipe, no LDS traffic)
// ---------------------------------------------------------------------------
template <int CTRL>
__device__ __forceinline__ float dppmov(float v) {
    return __int_as_float(__builtin_amdgcn_update_dpp(
        0, __float_as_int(v), CTRL, 0xF, 0xF, true));
}
__device__ __forceinline__ float grp_sum16(float v) {
    v += dppmov<0xB1>(v);   // quad_perm xor1
    v += dppmov<0x4E>(v);   // quad_perm xor2
    v += dppmov<0x124>(v);  // row_ror:4
    v += dppmov<0x128>(v);  // row_ror:8
    return v;
}
__device__ __forceinline__ float grp_max16(float v) {
    v = fmaxf(v, dppmov<0xB1>(v));
    v = fmaxf(v, dppmov<0x4E>(v));
    v = fmaxf(v, dppmov<0x124>(v));
    v = fmaxf(v, dppmov<0x128>(v));
    return v;
}

// ---------------------------------------------------------------------------
// Generic fp32 tiled GEMM (unchanged)
// ---------------------------------------------------------------------------
#define TM 64
#define TN 64
#define TK 16

__global__ __launch_bounds__(256) void gemm_tiled(
    const float* __restrict__ A, int lda,
    const float* __restrict__ B, int ldb,
    float* __restrict__ C, int ldc,
    int M, int N, int kc, const float* __restrict__ bias)
{
    __shared__ float As[TK][TM + 4];
    __shared__ float Bs[TK][TN + 4];
    const int tid = threadIdx.x;
    const int bm = blockIdx.y * TM;
    const int bn = blockIdx.x * TN;
    const int k0 = blockIdx.z * kc;
    C += (size_t)blockIdx.z * M * N;

    const int tx = tid & 15;
    const int ty = tid >> 4;

    float acc[4][4];
#pragma unroll
    for (int i = 0; i < 4; ++i)
#pragma unroll
        for (int j = 0; j < 4; ++j)
            acc[i][j] = bias ? bias[bn + tx * 4 + j] : 0.0f;

    const int ar = tid >> 2;
    const int ac = (tid & 3) * 4;
    const int br = tid >> 4;
    const int bc = (tid & 15) * 4;

    for (int kt = k0; kt < k0 + kc; kt += TK) {
        float4 a = *(const float4*)&A[(size_t)(bm + ar) * lda + kt + ac];
        float4 b = *(const float4*)&B[(size_t)(kt + br) * ldb + bn + bc];
        As[ac + 0][ar] = a.x; As[ac + 1][ar] = a.y;
        As[ac + 2][ar] = a.z; As[ac + 3][ar] = a.w;
        *(float4*)&Bs[br][bc] = b;
        __syncthreads();
#pragma unroll
        for (int kk = 0; kk < TK; ++kk) {
            float4 a4 = *(const float4*)&As[kk][ty * 4];
            float4 b4 = *(const float4*)&Bs[kk][tx * 4];
            float av[4] = {a4.x, a4.y, a4.z, a4.w};
            float bv[4] = {b4.x, b4.y, b4.z, b4.w};
#pragma unroll
            for (int i = 0; i < 4; ++i)
#pragma unroll
                for (int j = 0; j < 4; ++j)
                    acc[i][j] = fmaf(av[i], bv[j], acc[i][j]);
        }
        __syncthreads();
    }
#pragma unroll
    for (int i = 0; i < 4; ++i) {
        float4 o = make_float4(acc[i][0], acc[i][1], acc[i][2], acc[i][3]);
        *(float4*)&C[(size_t)(bm + ty * 4 + i) * ldc + bn + tx * 4] = o;
    }
}

// ---------------------------------------------------------------------------
// Fused quarter-token kernel: scores (f16 dot2) -> alpha-entmax (exact
// piecewise-quadratic active-set solve) -> P*V^T (f16 dot2).
// Grid 2048: 4 blocks/token, 128 rows each. K,V packed f16 + q f32 in LDS
// = 20 KB. Each 16-lane group owns one row, 32 cols/lane in VGPRs.
// ALL loops touching x[]/pp[]/qp[] are FULLY unrolled: any runtime index
// demotes the arrays to scratch (round-4 regression: 157 MB/dispatch of
// scratch writes, VALUBusy 89->57%).
// ---------------------------------------------------------------------------
#define QROWS 128
#define NSOLVE 4
#define NBISECT 3
#define NNEWTON 6

__global__ __launch_bounds__(256, 3) void attn_entmax(
    const float* qg, const float* kg, const float* vg,
    float* resg, const float* __restrict__ alpha_p)
{
    __shared__ uint32_t ks16[4 * 512];   // [h2][j] = (k[2h2,j], k[2h2+1,j]) f16
    __shared__ uint32_t vs16[8 * 256];   // [h][j2] = (v[h,2j], v[h,2j+1])  f16
    __shared__ float    qs[8 * QROWS];   // raw f32 q for this block's rows

    const int t = blockIdx.x >> 2;
    const int base = (blockIdx.x & 3) * QROWS;
    const int tid = threadIdx.x;

    const float alpha = alpha_p[0];
    const float expo = 1.0f / (alpha - 1.0f);          // 2 for alpha=1.5
    const bool fast = (expo == 2.0f);
    const float scl = (alpha - 1.0f) * 0.04419417382415922f;  // (a-1)/sqrt(512)
    const float hispan = powf(1.0f / 512.0f, alpha - 1.0f);

    {   // ---- stage K (h-pair packed), V (j-pair packed), q (f32)
        const float4* kg4 = (const float4*)(kg + (size_t)t * 4096);
        const float4* vg4 = (const float4*)(vg + (size_t)t * 4096);
        const float4* qg4 = (const float4*)(qg + (size_t)t * 4096);
#pragma unroll
        for (int a0 = 0; a0 < 2; ++a0) {
            int a = tid + 256 * a0;            // 0..511
            int h2 = a >> 7, j4 = a & 127;
            float4 g0 = kg4[(2 * h2) * 128 + j4];
            float4 g1 = kg4[(2 * h2 + 1) * 128 + j4];
            uint4 p = make_uint4(pk(g0.x, g1.x), pk(g0.y, g1.y),
                                 pk(g0.z, g1.z), pk(g0.w, g1.w));
            *(uint4*)&ks16[h2 * 512 + j4 * 4] = p;
        }
#pragma unroll
        for (int a0 = 0; a0 < 4; ++a0) {
            int f = tid + 256 * a0;            // 0..1023
            int h = f >> 7, j4 = f & 127;
            float4 g = vg4[h * 128 + j4];
            uint2 p = make_uint2(pk(g.x, g.y), pk(g.z, g.w));
            *(uint2*)&vs16[h * 256 + j4 * 2] = p;
        }
        {
            int h = tid >> 5, i4 = tid & 31;   // 256 float4 = 8h x 32
            *(float4*)&qs[h * QROWS + i4 * 4] = qg4[h * 128 + (base >> 2) + i4];
        }
    }
    __syncthreads();

    const int lane = tid & 63;
    const int w = tid >> 6;
    const int sub = lane >> 4;
    const int lx = lane & 15;

    const float qmul = fast ? 4.0f * scl : scl;   // fast path: x' = 4x
    const float TGT  = fast ? 16.0f : 1.0f;
    const float loO  = fast ? 4.0f : 1.0f;        // tau >= m - loO
    const float hiO  = fast ? 4.0f * hispan : hispan;  // tau <= m - hiO

    for (int it = 0; it < QROWS / 16; ++it) {
        const int il = it * 16 + w * 4 + sub;     // local row

        uint32_t qp[4];
#pragma unroll
        for (int h2 = 0; h2 < 4; ++h2)
            qp[h2] = pk(qs[(2 * h2) * QROWS + il] * qmul,
                        qs[(2 * h2 + 1) * QROWS + il] * qmul);

        // ---- scores via dot2; track max and sum (mean seed)
        float x[32];
        float m = -1e30f, s1a = 0.0f;
#pragma unroll
        for (int u = 0; u < 8; ++u) {
            float a0 = 0, a1 = 0, a2 = 0, a3 = 0;
#pragma unroll
            for (int h2 = 0; h2 < 4; ++h2) {
                uint4 kk = *(const uint4*)&ks16[h2 * 512 + lx * 4 + 64 * u];
                a0 = dot2(kk.x, qp[h2], a0);
                a1 = dot2(kk.y, qp[h2], a1);
                a2 = dot2(kk.z, qp[h2], a2);
                a3 = dot2(kk.w, qp[h2], a3);
            }
            x[4 * u + 0] = a0; x[4 * u + 1] = a1;
            x[4 * u + 2] = a2; x[4 * u + 3] = a3;
            m = fmaxf(m, fmaxf(fmaxf(a0, a1), fmaxf(a2, a3)));
            s1a += (a0 + a1) + (a2 + a3);
        }
        m = grp_max16(m);
        const float tlo = m - loO, thi = m - hiO;

        float tau;
        if (fast) {
            // seed: row mean (vertex of the all-active quadratic)
            s1a = grp_sum16(s1a);
            tau = fminf(fmaxf(s1a * (1.0f / 512.0f), tlo), thi);
            // exact active-set solves: f is quadratic per support set
#pragma unroll
            for (int itr = 0; itr < NSOLVE; ++itr) {
                float s1 = 0.0f, s2 = 0.0f, nf = 0.0f;
#pragma unroll
                for (int j = 0; j < 32; ++j) {
                    float r = x[j] - tau;
                    float rp = fmaxf(r, 0.0f);
                    s1 += rp;
                    s2 = fmaf(rp, rp, s2);
                    nf += (r > 0.0f) ? 1.0f : 0.0f;
                }
                s1 = grp_sum16(s1);
                s2 = grp_sum16(s2);
                nf = grp_sum16(nf);
                float disc = fmaxf(fmaf(s1, s1, -nf * (s2 - TGT)), 0.0f);
                tau += (s1 - sqrtf(disc)) / nf;
                tau = fminf(fmaxf(tau, tlo), thi);
            }
        } else {
            // generic alpha: bisect + Newton (powf path)
            tau = tlo;
            float dm = loO - hiO;
#pragma unroll
            for (int bi = 0; bi < NBISECT; ++bi) {
                dm *= 0.5f;
                float tm = tau + dm;
                float f = 0.0f;
#pragma unroll
                for (int j = 0; j < 32; ++j) {
                    float r = fmaxf(x[j] - tm, 0.0f);
                    f += __powf(r, expo);
                }
                f = grp_sum16(f);
                if (f >= TGT) tau = tm;
            }
#pragma unroll
            for (int ni = 0; ni < NNEWTON; ++ni) {
                float f = 0.0f, g = 0.0f;
#pragma unroll
                for (int j = 0; j < 32; ++j) {
                    float r = fmaxf(x[j] - tau, 0.0f);
                    float rp = __powf(r, expo - 1.0f);
                    g += rp; f += rp * r;
                }
                f = grp_sum16(f);
                g = grp_sum16(g);
                tau += (f - TGT) / fmaxf(expo * g, 1e-30f);
                tau = fminf(fmaxf(tau, tlo), thi);
            }
        }

        // ---- final p (unnormalized), S, pack to f16 pairs
        float S = 0.0f;
        uint32_t pp[16];
        if (fast) {
#pragma unroll
            for (int jj = 0; jj < 16; ++jj) {
                float r0 = fmaxf(x[2 * jj] - tau, 0.0f);
                float r1 = fmaxf(x[2 * jj + 1] - tau, 0.0f);
                float p0 = r0 * r0, p1 = r1 * r1;
                S += p0 + p1;
                pp[jj] = pk(p0, p1);
            }
        } else {
#pragma unroll
            for (int jj = 0; jj < 16; ++jj) {
                float p0 = __powf(fmaxf(x[2 * jj] - tau, 0.0f), expo);
                float p1 = __powf(fmaxf(x[2 * jj + 1] - tau, 0.0f), expo);
                S += p0 + p1;
                pp[jj] = pk(p0, p1);
            }
        }
        S = grp_sum16(S);
        const float invS = 1.0f / S;

        // ---- res[h,i] = invS * sum_j p_j v[h,j]  via dot2 on j-pairs
#pragma unroll
        for (int h = 0; h < 8; ++h) {
            float a = 0.0f;
#pragma unroll
            for (int u = 0; u < 8; ++u) {
                uint2 vv = *(const uint2*)&vs16[h * 256 + 32 * u + lx * 2];
                a = dot2(pp[2 * u], vv.x, a);
                a = dot2(pp[2 * u + 1], vv.y, a);
            }
            a = grp_sum16(a) * invS;
            if (lx == h) resg[(size_t)t * 4096 + h * 512 + base + il] = a;
        }
    }
}

// ---------------------------------------------------------------------------
__global__ __launch_bounds__(256) void reduce_bias(
    const float* __restrict__ part, const float* __restrict__ bu,
    float* __restrict__ out, int MN, int S)
{
    int i = blockIdx.x * 256 + threadIdx.x;
    if (i >= MN) return;
    float a = bu[i & 511];
#pragma unroll
    for (int s = 0; s < 8; ++s) a += part[(size_t)s * MN + i];
    out[i] = a;
}

// ---------------------------------------------------------------------------
extern "C" void kernel_launch(void* const* d_in, const int* in_sizes, int n_in,
                              void* d_out, int out_size, void* d_ws, size_t ws_size,
                              hipStream_t stream)
{
    const float* x  = (const float*)d_in[0];
    const float* Wq = (const float*)d_in[1];
    const float* bq = (const float*)d_in[2];
    const float* Wk = (const float*)d_in[3];
    const float* bk = (const float*)d_in[4];
    const float* Wv = (const float*)d_in[5];
    const float* bv = (const float*)d_in[6];
    const float* Wu = (const float*)d_in[7];
    const float* bu = (const float*)d_in[8];
    const float* al = (const float*)d_in[9];
    float* out = (float*)d_out;
    float* ws = (float*)d_ws;

    // ws layout (floats): q[2M] | k[2M] | v[2M]
    // res aliases q; split-K partials alias k (dead after attn_entmax).
    float* q = ws;
    float* k = ws + 2097152;
    float* v = ws + 2 * 2097152;
    float* res = q;
    float* part = k;

    dim3 blk(256);

    dim3 g1(4096 / TN, 512 / TM, 1);
    gemm_tiled<<<g1, blk, 0, stream>>>(x, 512, Wq, 4096, q, 4096, 512, 4096, 512, bq);
    gemm_tiled<<<g1, blk, 0, stream>>>(x, 512, Wk, 4096, k, 4096, 512, 4096, 512, bk);
    gemm_tiled<<<g1, blk, 0, stream>>>(x, 512, Wv, 4096, v, 4096, 512, 4096, 512, bv);

    attn_entmax<<<dim3(2048), blk, 0, stream>>>(q, k, v, res, al);

    dim3 g3(512 / TN, 512 / TM, 8);
    gemm_tiled<<<g3, blk, 0, stream>>>(res, 4096, Wu, 512, part, 512, 512, 512, 512, nullptr);
    reduce_bias<<<dim3(262144 / 256), blk, 0, stream>>>(part, bu, out, 262144, 8);
}

// Round 6
// 416.559 us; speedup vs baseline: 1.7427x; 1.7427x over previous
//
#include <hip/hip_runtime.h>
#include <hip/hip_bf16.h>

// ---------------------------------------------------------------------------
// DPP helpers: reductions within each 16-lane row (VALU pipe, no LDS traffic)
// ---------------------------------------------------------------------------
template <int CTRL>
__device__ __forceinline__ float dppmov(float v) {
    return __int_as_float(__builtin_amdgcn_update_dpp(
        0, __float_as_int(v), CTRL, 0xF, 0xF, true));
}
// sum across the 16 lanes of a DPP row; result in ALL 16 lanes
__device__ __forceinline__ float grp_sum16(float v) {
    v += dppmov<0xB1>(v);   // quad_perm xor1
    v += dppmov<0x4E>(v);   // quad_perm xor2
    v += dppmov<0x124>(v);  // row_ror:4
    v += dppmov<0x128>(v);  // row_ror:8
    return v;
}
__device__ __forceinline__ float grp_max16(float v) {
    v = fmaxf(v, dppmov<0xB1>(v));
    v = fmaxf(v, dppmov<0x4E>(v));
    v = fmaxf(v, dppmov<0x124>(v));
    v = fmaxf(v, dppmov<0x128>(v));
    return v;
}

// ---------------------------------------------------------------------------
// Generic fp32 tiled GEMM (unchanged from round 2)
// ---------------------------------------------------------------------------
#define TM 64
#define TN 64
#define TK 16

__global__ __launch_bounds__(256) void gemm_tiled(
    const float* __restrict__ A, int lda,
    const float* __restrict__ B, int ldb,
    float* __restrict__ C, int ldc,
    int M, int N, int kc, const float* __restrict__ bias)
{
    __shared__ float As[TK][TM + 4];
    __shared__ float Bs[TK][TN + 4];
    const int tid = threadIdx.x;
    const int bm = blockIdx.y * TM;
    const int bn = blockIdx.x * TN;
    const int k0 = blockIdx.z * kc;
    C += (size_t)blockIdx.z * M * N;

    const int tx = tid & 15;
    const int ty = tid >> 4;

    float acc[4][4];
#pragma unroll
    for (int i = 0; i < 4; ++i)
#pragma unroll
        for (int j = 0; j < 4; ++j)
            acc[i][j] = bias ? bias[bn + tx * 4 + j] : 0.0f;

    const int ar = tid >> 2;
    const int ac = (tid & 3) * 4;
    const int br = tid >> 4;
    const int bc = (tid & 15) * 4;

    for (int kt = k0; kt < k0 + kc; kt += TK) {
        float4 a = *(const float4*)&A[(size_t)(bm + ar) * lda + kt + ac];
        float4 b = *(const float4*)&B[(size_t)(kt + br) * ldb + bn + bc];
        As[ac + 0][ar] = a.x; As[ac + 1][ar] = a.y;
        As[ac + 2][ar] = a.z; As[ac + 3][ar] = a.w;
        *(float4*)&Bs[br][bc] = b;
        __syncthreads();
#pragma unroll
        for (int kk = 0; kk < TK; ++kk) {
            float4 a4 = *(const float4*)&As[kk][ty * 4];
            float4 b4 = *(const float4*)&Bs[kk][tx * 4];
            float av[4] = {a4.x, a4.y, a4.z, a4.w};
            float bv[4] = {b4.x, b4.y, b4.z, b4.w};
#pragma unroll
            for (int i = 0; i < 4; ++i)
#pragma unroll
                for (int j = 0; j < 4; ++j)
                    acc[i][j] = fmaf(av[i], bv[j], acc[i][j]);
        }
        __syncthreads();
    }
#pragma unroll
    for (int i = 0; i < 4; ++i) {
        float4 o = make_float4(acc[i][0], acc[i][1], acc[i][2], acc[i][3]);
        *(float4*)&C[(size_t)(bm + ty * 4 + i) * ldc + bn + tx * 4] = o;
    }
}

// ---------------------------------------------------------------------------
// Fused per-half-token kernel: scores -> alpha-entmax -> P*V^T.
// EXACT round-2 structure (proven: VGPR 60, zero scratch, VALUBusy 89%);
// only the tau solver changed: mean-seeded exact piecewise-quadratic
// active-set solve (4 sweeps) replaces 3 bisect + 6 Newton (9 sweeps).
// f(tau) = sum relu(x-tau)^2 - 1 is exactly quadratic per support set, so
// each sweep solves its model exactly; support stabilizes in 2-3 sweeps.
// All fp32 — the f16/dot2 variant (rounds 4-5) triggered scratch demotion.
// ---------------------------------------------------------------------------
#define NSOLVE 4
#define NBISECT 3
#define NNEWTON 6

__global__ __launch_bounds__(256, 3) void attn_entmax(
    const float* qg, const float* kg, const float* vg,
    float* resg, const float* __restrict__ alpha_p)
{
    __shared__ float ks[8 * 512];
    __shared__ float vs[8 * 512];
    __shared__ float qs[8 * 256];
    const int t = blockIdx.x >> 1;
    const int base = (blockIdx.x & 1) << 8;    // row half: 0 or 256
    const int tid = threadIdx.x;

    const float alpha = alpha_p[0];
    const float expo = 1.0f / (alpha - 1.0f);      // = 2 for alpha=1.5 (exact)
    const bool fast = (expo == 2.0f);
    const float scl = (alpha - 1.0f) * 0.04419417382415922f;  // (a-1)/sqrt(512)
    const float hispan = powf(1.0f / 512.0f, alpha - 1.0f);   // m - tau_hi

    {   // stage K, V (full token) and q (this block's 256 rows)
        const float4* k4 = (const float4*)(kg + (size_t)t * 4096);
        const float4* v4 = (const float4*)(vg + (size_t)t * 4096);
#pragma unroll
        for (int u = 0; u < 4; ++u) {
            int idx = tid + 256 * u;
            ((float4*)ks)[idx] = k4[idx];
            ((float4*)vs)[idx] = v4[idx];
        }
        const float4* q4 = (const float4*)(qg + (size_t)t * 4096);
#pragma unroll
        for (int u = 0; u < 2; ++u) {
            int idx = tid + 256 * u;               // = h*64 + j4
            ((float4*)qs)[idx] = q4[(idx >> 6) * 128 + (base >> 2) + (idx & 63)];
        }
    }
    __syncthreads();

    const int lane = tid & 63;
    const int w = tid >> 6;        // wave 0..3
    const int sub = lane >> 4;     // 16-lane group 0..3 (one row each)
    const int lx = lane & 15;

    for (int it = 0; it < 16; ++it) {
        const int il = it * 16 + w * 4 + sub;   // local row 0..255

        float qv[8];
#pragma unroll
        for (int h = 0; h < 8; ++h) qv[h] = qs[h * 256 + il];

        // ---- scores: x[j] = (alpha-1)/sqrt(512) * sum_h q[h,i]*k[h,j]
        // lane columns: j = lx*4 + 64*u + {0..3}, u = 0..7 (32 per lane)
        float x[32];
        float s1a = 0.0f;
#pragma unroll 2
        for (int u = 0; u < 8; ++u) {
            float a0 = 0, a1 = 0, a2 = 0, a3 = 0;
#pragma unroll
            for (int h = 0; h < 8; ++h) {
                float4 k4 = *(const float4*)&ks[h * 512 + lx * 4 + 64 * u];
                float qh = qv[h];
                a0 = fmaf(qh, k4.x, a0); a1 = fmaf(qh, k4.y, a1);
                a2 = fmaf(qh, k4.z, a2); a3 = fmaf(qh, k4.w, a3);
            }
            a0 *= scl; a1 *= scl; a2 *= scl; a3 *= scl;
            x[4 * u + 0] = a0; x[4 * u + 1] = a1;
            x[4 * u + 2] = a2; x[4 * u + 3] = a3;
            s1a += (a0 + a1) + (a2 + a3);
        }

        // ---- row max
        float m = x[0];
#pragma unroll
        for (int j = 1; j < 32; ++j) m = fmaxf(m, x[j]);
        m = grp_max16(m);
        const float tlo = m - 1.0f;            // f(tlo) >= 1 always
        const float thi = m - hispan;          // f(thi) <= 1 always

        float tau;
        if (fast) {
            // seed: row mean, clamped into the bracket
            s1a = grp_sum16(s1a);
            tau = fminf(fmaxf(s1a * (1.0f / 512.0f), tlo), thi);
            // exact active-set solves: f is quadratic per support set
#pragma unroll
            for (int itr = 0; itr < NSOLVE; ++itr) {
                float s1 = 0.0f, s2 = 0.0f, nf = 0.0f;
#pragma unroll
                for (int j = 0; j < 32; ++j) {
                    float r = x[j] - tau;
                    float rp = fmaxf(r, 0.0f);
                    s1 += rp;
                    s2 = fmaf(rp, rp, s2);
                    nf += (r > 0.0f) ? 1.0f : 0.0f;
                }
                s1 = grp_sum16(s1);
                s2 = grp_sum16(s2);
                nf = grp_sum16(nf);
                float disc = fmaxf(fmaf(s1, s1, -nf * (s2 - 1.0f)), 0.0f);
                tau += (s1 - sqrtf(disc)) / fmaxf(nf, 1.0f);
                tau = fminf(fmaxf(tau, tlo), thi);
            }
        } else {
            // generic alpha: bisect + Newton (powf path)
            tau = tlo;
            float dm = 1.0f - hispan;
#pragma unroll
            for (int bi = 0; bi < NBISECT; ++bi) {
                dm *= 0.5f;
                float tm = tau + dm;
                float f = 0.0f;
#pragma unroll
                for (int j = 0; j < 32; ++j) {
                    float r = fmaxf(x[j] - tm, 0.0f);
                    f += __powf(r, expo);
                }
                f = grp_sum16(f);
                if (f >= 1.0f) tau = tm;
            }
#pragma unroll
            for (int ni = 0; ni < NNEWTON; ++ni) {
                float f = 0.0f, g = 0.0f;
#pragma unroll
                for (int j = 0; j < 32; ++j) {
                    float r = fmaxf(x[j] - tau, 0.0f);
                    float rp = __powf(r, expo - 1.0f);
                    g += rp; f += rp * r;
                }
                f = grp_sum16(f);
                g = grp_sum16(g);
                tau += (f - 1.0f) / fmaxf(expo * g, 1e-30f);
                tau = fminf(fmaxf(tau, tlo), thi);
            }
        }

        // ---- final (unnormalized) p into x; S for normalization
        float S = 0.0f;
        if (fast) {
#pragma unroll
            for (int j = 0; j < 32; ++j) {
                float r = fmaxf(x[j] - tau, 0.0f);
                x[j] = r * r; S += x[j];
            }
        } else {
#pragma unroll
            for (int j = 0; j < 32; ++j) {
                float r = fmaxf(x[j] - tau, 0.0f);
                x[j] = __powf(r, expo); S += x[j];
            }
        }
        S = grp_sum16(S);
        const float invS = 1.0f / S;

        // ---- res[h,i] = invS * sum_j p[j] * v[h,j]; direct exec-masked store
#pragma unroll
        for (int h = 0; h < 8; ++h) {
            float a = 0.0f;
#pragma unroll 2
            for (int u = 0; u < 8; ++u) {
                float4 v4 = *(const float4*)&vs[h * 512 + lx * 4 + 64 * u];
                a = fmaf(x[4 * u + 0], v4.x, a);
                a = fmaf(x[4 * u + 1], v4.y, a);
                a = fmaf(x[4 * u + 2], v4.z, a);
                a = fmaf(x[4 * u + 3], v4.w, a);
            }
            a = grp_sum16(a) * invS;
            if (lx == h) resg[(size_t)t * 4096 + h * 512 + base + il] = a;
        }
    }
}

// ---------------------------------------------------------------------------
// out[m][n] = bu[n] + sum_s partial[s][m][n]
// ---------------------------------------------------------------------------
__global__ __launch_bounds__(256) void reduce_bias(
    const float* __restrict__ part, const float* __restrict__ bu,
    float* __restrict__ out, int MN, int S)
{
    int i = blockIdx.x * 256 + threadIdx.x;
    if (i >= MN) return;
    float a = bu[i & 511];
#pragma unroll
    for (int s = 0; s < 8; ++s) a += part[(size_t)s * MN + i];
    out[i] = a;
}

// ---------------------------------------------------------------------------
extern "C" void kernel_launch(void* const* d_in, const int* in_sizes, int n_in,
                              void* d_out, int out_size, void* d_ws, size_t ws_size,
                              hipStream_t stream)
{
    const float* x  = (const float*)d_in[0];
    const float* Wq = (const float*)d_in[1];
    const float* bq = (const float*)d_in[2];
    const float* Wk = (const float*)d_in[3];
    const float* bk = (const float*)d_in[4];
    const float* Wv = (const float*)d_in[5];
    const float* bv = (const float*)d_in[6];
    const float* Wu = (const float*)d_in[7];
    const float* bu = (const float*)d_in[8];
    const float* al = (const float*)d_in[9];
    float* out = (float*)d_out;
    float* ws = (float*)d_ws;

    // ws layout (floats): q[2M] | k[2M] | v[2M]
    // res aliases q (each attn block reads only its own q slice, then writes
    // the same slice); split-K partials alias k (k dead after attn_entmax).
    float* q = ws;
    float* k = ws + 2097152;
    float* v = ws + 2 * 2097152;
    float* res = q;
    float* part = k;

    dim3 blk(256);

    dim3 g1(4096 / TN, 512 / TM, 1);
    gemm_tiled<<<g1, blk, 0, stream>>>(x, 512, Wq, 4096, q, 4096, 512, 4096, 512, bq);
    gemm_tiled<<<g1, blk, 0, stream>>>(x, 512, Wk, 4096, k, 4096, 512, 4096, 512, bk);
    gemm_tiled<<<g1, blk, 0, stream>>>(x, 512, Wv, 4096, v, 4096, 512, 4096, 512, bv);

    // fused scores + alpha-entmax + P*V^T, half token per block
    attn_entmax<<<dim3(1024), blk, 0, stream>>>(q, k, v, res, al);

    dim3 g3(512 / TN, 512 / TM, 8);
    gemm_tiled<<<g3, blk, 0, stream>>>(res, 4096, Wu, 512, part, 512, 512, 512, 512, nullptr);
    reduce_bias<<<dim3(262144 / 256), blk, 0, stream>>>(part, bu, out, 262144, 8);
}